// Round 7
// baseline (662.779 us; speedup 1.0000x reference)
//
#include <hip/hip_runtime.h>
#include <hip/hip_bf16.h>
#include <cstdint>
#include <cstddef>

#define NN 50000
#define EE 800000
#define FF 768
#define HH 256
#define GG 512
#define CC 2
#define NHIDD 128
#define ETOT (EE + NN)
#define NCHUNK 49   // ceil(NN/1024)

typedef __attribute__((ext_vector_type(8))) short bf16x8;   // 8 bf16 in 4 VGPRs
typedef __attribute__((ext_vector_type(4))) float f32x4;
typedef __attribute__((ext_vector_type(8))) unsigned short us8;

__device__ __forceinline__ float b2f(unsigned short u){
  union { float f; uint32_t i; } v; v.i = ((uint32_t)u) << 16; return v.f;
}
__device__ __forceinline__ unsigned short f2b(float f){
  uint32_t u = __float_as_uint(f);
  uint32_t r = (u + 0x7fffu + ((u >> 16) & 1u)) >> 16;
  return (unsigned short)r;
}
// packed fp32->bf16 (RNE, same rounding as f2b); gfx950 has the instruction but no builtin
__device__ __forceinline__ uint32_t cvtpk(float a, float b){
  uint32_t d;
  asm volatile("v_cvt_pk_bf16_f32 %0, %1, %2" : "=v"(d) : "v"(a), "v"(b));
  return d;
}
__device__ __forceinline__ float selu_f(float x){
  const float lam = 1.0507009873554805f, alp = 1.6732632423543772f;
  return x > 0.f ? lam * x : lam * alp * (__expf(x) - 1.f);
}

// rule #17 keep-alive: a compiler-visible USE at this program point; loads feeding v cannot be sunk past it.
__device__ __forceinline__ void keepalive(bf16x8& v){
  union { bf16x8 v; uint32_t u[4]; } t; t.v = v;
  asm volatile("" : "+v"(t.u[0]), "+v"(t.u[1]), "+v"(t.u[2]), "+v"(t.u[3]));
  v = t.v;
}
__device__ __forceinline__ void keepalive(us8& v){
  union { us8 v; uint32_t u[4]; } t; t.v = v;
  asm volatile("" : "+v"(t.u[0]), "+v"(t.u[1]), "+v"(t.u[2]), "+v"(t.u[3]));
  v = t.v;
}

// direct-to-LDS 16B DMA (compiler never auto-emits this; bypasses VGPR round-trip AND regalloc load-sinking)
__device__ __forceinline__ void gload_lds16(const void* g, void* l){
  __builtin_amdgcn_global_load_lds((const __attribute__((address_space(1))) void*)g,
                                   (__attribute__((address_space(3))) void*)l, 16, 0, 0);
}

// ---------------- W1+W2 swizzle in ONE dispatch: [K][256] f32 -> [K/32][256][32] bf16 ----------------
__global__ __launch_bounds__(256) void swizzleW2(const float* __restrict__ W1, const float* __restrict__ W2,
                                                 unsigned short* __restrict__ Wsw1, unsigned short* __restrict__ Wsw2){
  int i = blockIdx.x * 256 + threadIdx.x;          // grid covers FF*HH + HH*HH = 262144 exactly
  if (i < FF * HH){
    int k = i / HH, n = i % HH;
    Wsw1[(size_t)(k >> 5) * 8192 + n * 32 + (k & 31)] = f2b(W1[i]);
  } else {
    int i2 = i - FF * HH;
    int k = i2 / HH, n = i2 % HH;
    Wsw2[(size_t)(k >> 5) * 8192 + n * 32 + (k & 31)] = f2b(W2[i2]);
  }
}

// ---------------- CSR build ----------------
__global__ __launch_bounds__(256) void deg_kernel(const int* __restrict__ dstA, int* __restrict__ deg){
  int i = blockIdx.x * 256 + threadIdx.x;
  if (i < ETOT){
    int d = (i < EE) ? dstA[i] : (i - EE);   // self-loops appended
    atomicAdd(&deg[d], 1);
  }
}

__global__ __launch_bounds__(256) void scanA(const int* __restrict__ deg, int* __restrict__ bsum){
  __shared__ int red[256];
  int c = blockIdx.x, tid = threadIdx.x;
  int base = c * 1024 + tid * 4;
  int s = 0;
#pragma unroll
  for (int j = 0; j < 4; j++){ int idx = base + j; if (idx < NN) s += deg[idx]; }
  red[tid] = s; __syncthreads();
  for (int off = 128; off > 0; off >>= 1){
    if (tid < off) red[tid] += red[tid + off];
    __syncthreads();
  }
  if (tid == 0) bsum[c] = red[0];
}

// scanB folded in: chunk base computed by an in-block reduce of bsum[0..c)
__global__ __launch_bounds__(256) void scanC(const int* __restrict__ deg, const int* __restrict__ bsum,
                                             int* __restrict__ row_ptr, int* __restrict__ fill_ptr){
  __shared__ int ts[256];
  __shared__ int cbase;
  int c = blockIdx.x, tid = threadIdx.x;
  int pb = (tid < c) ? bsum[tid] : 0;    // NCHUNK=49 <= 256
  ts[tid] = pb; __syncthreads();
  for (int off = 128; off > 0; off >>= 1){
    if (tid < off) ts[tid] += ts[tid + off];
    __syncthreads();
  }
  if (tid == 0) cbase = ts[0];
  __syncthreads();
  int base = c * 1024 + tid * 4;
  int v[4]; int s = 0;
#pragma unroll
  for (int j = 0; j < 4; j++){ int idx = base + j; v[j] = (idx < NN) ? deg[idx] : 0; s += v[j]; }
  ts[tid] = s; __syncthreads();
  for (int off = 1; off < 256; off <<= 1){
    int add = (tid >= off) ? ts[tid - off] : 0;
    __syncthreads();
    ts[tid] += add;
    __syncthreads();
  }
  int run = ts[tid] - s + cbase;
#pragma unroll
  for (int j = 0; j < 4; j++){
    int idx = base + j;
    if (idx < NN){ row_ptr[idx] = run; fill_ptr[idx] = run; }
    run += v[j];
  }
  if (c == 0 && tid == 0) row_ptr[NN] = ETOT;
}

__global__ __launch_bounds__(256) void fill_kernel(const int* __restrict__ srcA, const int* __restrict__ dstA,
                                                   int* __restrict__ fill_ptr, int* __restrict__ csr_src){
  int i = blockIdx.x * 256 + threadIdx.x;
  if (i < ETOT){
    int s = (i < EE) ? srcA[i] : (i - EE);
    int d = (i < EE) ? dstA[i] : (i - EE);
    int pos = atomicAdd(&fill_ptr[d], 1);
    csr_src[pos] = s;
  }
}

// ---------------- GEMM layer 1: fp32 A via DMA, 2 half-K phases, cvt_pk on read, B kept live ----------------
// r6 post-mortem: VGPR=84 proves bnext never existed in registers (bcur32+acc32+af16=80) -> regalloc sank
// every B prefetch to its MFMA use, exposing ~L2 latency x 8 loads per K-step. r7: keepalive() pins bnext
// at its load site; __launch_bounds__(256,2) grants the ~120-VGPR budget (LDS caps 3 blk/CU regardless;
// 128-VGPR class still allows 4 waves/SIMD >= LDS cap -> occupancy unchanged).
__global__ __launch_bounds__(256, 2) void gemm1_f32(const float* __restrict__ A,
                                                 const unsigned short* __restrict__ Wsw,
                                                 const float* __restrict__ a_s, const float* __restrict__ a_d,
                                                 unsigned short* __restrict__ out,
                                                 float* __restrict__ als, float* __restrict__ ald, int M){
  __shared__ float Alf[32 * 384];                  // 48 KB
  const int tid = threadIdx.x;
  const int m0 = blockIdx.x * 32;
  const int lane = tid & 63, w = tid >> 6;
  const int koff = (lane >> 4) * 8;
  const int arow = lane & 15;
  const int nrow = w * 64 + (lane & 15);

  f32x4 acc[2][4];
#pragma unroll
  for (int rt = 0; rt < 2; rt++)
#pragma unroll
    for (int ct = 0; ct < 4; ct++) acc[rt][ct] = (f32x4){0.f, 0.f, 0.f, 0.f};

  const unsigned short* bbase = Wsw + ((size_t)nrow * 32 + koff);
  bf16x8 bcur[2][4];

  auto stage_half = [&](int p){
#pragma unroll
    for (int j = 0; j < 12; j++){
      int L16 = j * 256 + tid;                     // linear 16B(f32x4)-chunk index in half-panel
      int row = L16 / 96;
      int ch  = L16 - row * 96;
      int sch = ch ^ (row & 7);                    // inverse-swizzle the SOURCE (involution, stays in [0,96))
      int gr  = m0 + row; if (gr >= M) gr = M - 1; // clamp: garbage rows never stored
      gload_lds16(A + (size_t)gr * FF + p * 384 + sch * 4,
                  Alf + (size_t)(j * 256 + w * 64) * 4);   // wave-uniform dest; HW adds lane*16B
    }
  };

#pragma unroll
  for (int p = 0; p < 2; p++){
    if (p == 1) __syncthreads();                   // all phase-0 reads done before overwrite
    stage_half(p);
    // prefetch B slabs for first ks of this phase (overlaps DMA drain)
#pragma unroll
    for (int k2 = 0; k2 < 2; k2++)
#pragma unroll
      for (int ct = 0; ct < 4; ct++){
        bcur[k2][ct] = *(const bf16x8*)(bbase + (size_t)(p * 12 + k2) * 8192 + ct * 512);
        keepalive(bcur[k2][ct]);
      }
    __syncthreads();                               // DMA visible

    for (int ks = 0; ks < 6; ks++){
      bf16x8 bnext[2][4];
      if (ks + 1 < 6){
#pragma unroll
        for (int k2 = 0; k2 < 2; k2++)
#pragma unroll
          for (int ct = 0; ct < 4; ct++){
            bnext[k2][ct] = *(const bf16x8*)(bbase + (size_t)(p * 12 + (ks + 1) * 2 + k2) * 8192 + ct * 512);
            keepalive(bnext[k2][ct]);              // pin the load HERE; cannot sink past this use
          }
      }
      bf16x8 af[2][2];
#pragma unroll
      for (int k2 = 0; k2 < 2; k2++)
#pragma unroll
        for (int rt = 0; rt < 2; rt++){
          int R = rt * 16 + arow;
          int c = ks * 16 + k2 * 8 + (lane >> 4) * 2;          // even chunk index of 8-f32 fragment
          int m = R & 7;
          float4 v0 = *(const float4*)&Alf[R * 384 + ((c)     ^ m) * 4];
          float4 v1 = *(const float4*)&Alf[R * 384 + ((c + 1) ^ m) * 4];
          union { bf16x8 v; uint32_t u[4]; } X;
          X.u[0] = cvtpk(v0.x, v0.y); X.u[1] = cvtpk(v0.z, v0.w);
          X.u[2] = cvtpk(v1.x, v1.y); X.u[3] = cvtpk(v1.z, v1.w);
          af[k2][rt] = X.v;
        }
#pragma unroll
      for (int k2 = 0; k2 < 2; k2++)
#pragma unroll
        for (int rt = 0; rt < 2; rt++)
#pragma unroll
          for (int ct = 0; ct < 4; ct++)
            acc[rt][ct] = __builtin_amdgcn_mfma_f32_16x16x32_bf16(af[k2][rt], bcur[k2][ct], acc[rt][ct], 0, 0, 0);
      if (ks + 1 < 6){
#pragma unroll
        for (int k2 = 0; k2 < 2; k2++)
#pragma unroll
          for (int ct = 0; ct < 4; ct++) bcur[k2][ct] = bnext[k2][ct];
      }
    }
  }

  // ---- C write (bf16 h) ----
#pragma unroll
  for (int rt = 0; rt < 2; rt++){
    int mbase = m0 + rt * 16 + (lane >> 4) * 4;
#pragma unroll
    for (int r = 0; r < 4; r++){
      int m = mbase + r;
      if (m < M){
        size_t ro = (size_t)m * HH + w * 64 + (lane & 15);
        out[ro + 0]  = f2b(acc[rt][0][r]);
        out[ro + 16] = f2b(acc[rt][1][r]);
        out[ro + 32] = f2b(acc[rt][2][r]);
        out[ro + 48] = f2b(acc[rt][3][r]);
      }
    }
  }

  // ---- fused als/ald from fp32 accumulators ----
  float as_c[4], ad_c[4];
#pragma unroll
  for (int ct = 0; ct < 4; ct++){
    int col = w * 64 + ct * 16 + (lane & 15);
    as_c[ct] = a_s[col]; ad_c[ct] = a_d[col];
  }
  float ps[2][4], pd[2][4];
#pragma unroll
  for (int rt = 0; rt < 2; rt++)
#pragma unroll
    for (int r = 0; r < 4; r++){
      float s = 0.f, d = 0.f;
#pragma unroll
      for (int ct = 0; ct < 4; ct++){ float v = acc[rt][ct][r]; s += v * as_c[ct]; d += v * ad_c[ct]; }
      ps[rt][r] = s; pd[rt][r] = d;
    }
#pragma unroll
  for (int off = 1; off < 16; off <<= 1){
#pragma unroll
    for (int rt = 0; rt < 2; rt++)
#pragma unroll
      for (int r = 0; r < 4; r++){
        ps[rt][r] += __shfl_xor(ps[rt][r], off);
        pd[rt][r] += __shfl_xor(pd[rt][r], off);
      }
  }
  __syncthreads();
  float* red = Alf;
  if ((lane & 15) == 0){
    int q = lane >> 4;
#pragma unroll
    for (int rt = 0; rt < 2; rt++)
#pragma unroll
      for (int r = 0; r < 4; r++){
        int row = rt * 16 + q * 4 + r;
        red[w * 32 + row]       = ps[rt][r];
        red[128 + w * 32 + row] = pd[rt][r];
      }
  }
  __syncthreads();
  if (tid < 32){
    float s = red[tid] + red[32 + tid] + red[64 + tid] + red[96 + tid];
    float d = red[128 + tid] + red[160 + tid] + red[192 + tid] + red[224 + tid];
    int m = m0 + tid;
    if (m < M){ als[m] = s; ald[m] = d; }
  }
}

// ---------------- GEMM layer 2 (bf16 A, frozen v6 structure) ----------------
template<int K, int MINW>
__global__ __launch_bounds__(256, MINW) void gemm_mfma(const unsigned short* __restrict__ A,
                                                 const unsigned short* __restrict__ Wsw,
                                                 const float* __restrict__ a_s, const float* __restrict__ a_d,
                                                 unsigned short* __restrict__ out,
                                                 float* __restrict__ als, float* __restrict__ ald, int M){
  constexpr int CHROW = K / 8;
  __shared__ unsigned short Al[32 * K];
  const int tid = threadIdx.x;
  const int m0 = blockIdx.x * 32;
  const int lane = tid & 63, w = tid >> 6;
  const int koff = (lane >> 4) * 8;
  const int arow = lane & 15;
  const int nrow = w * 64 + (lane & 15);

  f32x4 acc[2][4];
#pragma unroll
  for (int rt = 0; rt < 2; rt++)
#pragma unroll
    for (int ct = 0; ct < 4; ct++) acc[rt][ct] = (f32x4){0.f, 0.f, 0.f, 0.f};

  constexpr int ROUNDS = (32 * CHROW) / 256;
#pragma unroll
  for (int j = 0; j < ROUNDS; j++){
    int L16 = j * 256 + tid;
    int row = L16 / CHROW;
    int ch  = L16 - row * CHROW;
    int sch = ch ^ (row & 7);
    int gr  = m0 + row; if (gr >= M) gr = M - 1;
    gload_lds16(A + (size_t)gr * K + sch * 8,
                &Al[(size_t)(j * 256 + w * 64) * 8]);
  }

  const unsigned short* bbase = Wsw + ((size_t)nrow * 32 + koff);
  bf16x8 bcur[2][4];
#pragma unroll
  for (int k2 = 0; k2 < 2; k2++)
#pragma unroll
    for (int ct = 0; ct < 4; ct++)
      bcur[k2][ct] = *(const bf16x8*)(bbase + (size_t)k2 * 8192 + ct * 512);

  __syncthreads();

  constexpr int NIT = K / 64;
  for (int ks = 0; ks < NIT; ks++){
    bf16x8 bnext[2][4];
    if (ks + 1 < NIT){
#pragma unroll
      for (int k2 = 0; k2 < 2; k2++)
#pragma unroll
        for (int ct = 0; ct < 4; ct++)
          bnext[k2][ct] = *(const bf16x8*)(bbase + (size_t)((ks + 1) * 2 + k2) * 8192 + ct * 512);
    }
    bf16x8 af[2][2];
#pragma unroll
    for (int k2 = 0; k2 < 2; k2++)
#pragma unroll
      for (int rt = 0; rt < 2; rt++){
        int R = rt * 16 + arow;
        int chb = (ks * 8 + k2 * 4 + (lane >> 4)) ^ (R & 7);
        af[k2][rt] = *(const bf16x8*)&Al[(size_t)R * K + chb * 8];
      }
#pragma unroll
    for (int k2 = 0; k2 < 2; k2++)
#pragma unroll
      for (int rt = 0; rt < 2; rt++)
#pragma unroll
        for (int ct = 0; ct < 4; ct++)
          acc[rt][ct] = __builtin_amdgcn_mfma_f32_16x16x32_bf16(af[k2][rt], bcur[k2][ct], acc[rt][ct], 0, 0, 0);
    if (ks + 1 < NIT){
#pragma unroll
      for (int k2 = 0; k2 < 2; k2++)
#pragma unroll
        for (int ct = 0; ct < 4; ct++) bcur[k2][ct] = bnext[k2][ct];
    }
  }

#pragma unroll
  for (int rt = 0; rt < 2; rt++){
    int mbase = m0 + rt * 16 + (lane >> 4) * 4;
#pragma unroll
    for (int r = 0; r < 4; r++){
      int m = mbase + r;
      if (m < M){
        size_t ro = (size_t)m * HH + w * 64 + (lane & 15);
        out[ro + 0]  = f2b(acc[rt][0][r]);
        out[ro + 16] = f2b(acc[rt][1][r]);
        out[ro + 32] = f2b(acc[rt][2][r]);
        out[ro + 48] = f2b(acc[rt][3][r]);
      }
    }
  }

  float as_c[4], ad_c[4];
#pragma unroll
  for (int ct = 0; ct < 4; ct++){
    int col = w * 64 + ct * 16 + (lane & 15);
    as_c[ct] = a_s[col]; ad_c[ct] = a_d[col];
  }
  float ps[2][4], pd[2][4];
#pragma unroll
  for (int rt = 0; rt < 2; rt++)
#pragma unroll
    for (int r = 0; r < 4; r++){
      float s = 0.f, d = 0.f;
#pragma unroll
      for (int ct = 0; ct < 4; ct++){ float v = acc[rt][ct][r]; s += v * as_c[ct]; d += v * ad_c[ct]; }
      ps[rt][r] = s; pd[rt][r] = d;
    }
#pragma unroll
  for (int off = 1; off < 16; off <<= 1){
#pragma unroll
    for (int rt = 0; rt < 2; rt++)
#pragma unroll
      for (int r = 0; r < 4; r++){
        ps[rt][r] += __shfl_xor(ps[rt][r], off);
        pd[rt][r] += __shfl_xor(pd[rt][r], off);
      }
  }
  __syncthreads();
  float* red = (float*)Al;
  if ((lane & 15) == 0){
    int q = lane >> 4;
#pragma unroll
    for (int rt = 0; rt < 2; rt++)
#pragma unroll
      for (int r = 0; r < 4; r++){
        int row = rt * 16 + q * 4 + r;
        red[w * 32 + row]       = ps[rt][r];
        red[128 + w * 32 + row] = pd[rt][r];
      }
  }
  __syncthreads();
  if (tid < 32){
    float s = red[tid] + red[32 + tid] + red[64 + tid] + red[96 + tid];
    float d = red[128 + tid] + red[160 + tid] + red[192 + tid] + red[224 + tid];
    int m = m0 + tid;
    if (m < M){ als[m] = s; ald[m] = d; }
  }
}

// ---------------- agg v5: v4 + one-step-ahead gather prefetch (keepalive-pinned) ----------------
__global__ __launch_bounds__(256) void agg_wave(const unsigned short* __restrict__ h,
    const float* __restrict__ als, const float* __restrict__ ald,
    const int* __restrict__ row_ptr, const int* __restrict__ csr_src,
    const float* __restrict__ bias, unsigned short* __restrict__ outp){
  int node = blockIdx.x * 4 + (threadIdx.x >> 6);
  int lane = threadIdx.x & 63;
  if (node >= NN) return;
  int base = row_ptr[node];
  int deg  = row_ptr[node + 1] - base;
  float aldd = ald[node];
  float den = 0.f;
  float a[8] = {0.f, 0.f, 0.f, 0.f, 0.f, 0.f, 0.f, 0.f};
  const int f8 = (lane & 31) * 8;        // this lane's 8-feature slice
  const int half = lane >> 5;            // 0: even edges, 1: odd edges
  for (int p0 = 0; p0 < deg; p0 += 64){
    int cnt = min(64, deg - p0);         // wave-uniform
    float ev = 0.f; int s = 0;
    if (lane < cnt){
      s = csr_src[base + p0 + lane];
      float v = als[s] + aldd;
      v = v > 0.f ? v : 0.2f * v;        // leaky_relu(0.2)
      ev = __expf(v);
    }
    den += ev;
    int j = 0;
    us8 ga[4]; float ea[4];
    if (j + 8 <= cnt){                   // prologue: issue step-0 gathers
      int j0 = j + half, j1 = j + 2 + half, j2 = j + 4 + half, j3 = j + 6 + half;
      int s0 = __shfl(s, j0), s1 = __shfl(s, j1), s2 = __shfl(s, j2), s3 = __shfl(s, j3);
      ea[0] = __shfl(ev, j0); ea[1] = __shfl(ev, j1); ea[2] = __shfl(ev, j2); ea[3] = __shfl(ev, j3);
      ga[0] = *(const us8*)&h[(size_t)s0 * HH + f8]; keepalive(ga[0]);
      ga[1] = *(const us8*)&h[(size_t)s1 * HH + f8]; keepalive(ga[1]);
      ga[2] = *(const us8*)&h[(size_t)s2 * HH + f8]; keepalive(ga[2]);
      ga[3] = *(const us8*)&h[(size_t)s3 * HH + f8]; keepalive(ga[3]);
    }
    for (; j + 8 <= cnt; j += 8){        // 8 edges/step; next step's gathers in flight during FMAs
      us8 gb[4]; float eb[4];
      bool more = (j + 16 <= cnt);
      if (more){
        int jn = j + 8;
        int j0 = jn + half, j1 = jn + 2 + half, j2 = jn + 4 + half, j3 = jn + 6 + half;
        int s0 = __shfl(s, j0), s1 = __shfl(s, j1), s2 = __shfl(s, j2), s3 = __shfl(s, j3);
        eb[0] = __shfl(ev, j0); eb[1] = __shfl(ev, j1); eb[2] = __shfl(ev, j2); eb[3] = __shfl(ev, j3);
        gb[0] = *(const us8*)&h[(size_t)s0 * HH + f8]; keepalive(gb[0]);
        gb[1] = *(const us8*)&h[(size_t)s1 * HH + f8]; keepalive(gb[1]);
        gb[2] = *(const us8*)&h[(size_t)s2 * HH + f8]; keepalive(gb[2]);
        gb[3] = *(const us8*)&h[(size_t)s3 * HH + f8]; keepalive(gb[3]);
      }
#pragma unroll
      for (int i = 0; i < 8; i++) a[i] += ea[0] * b2f(ga[0][i]) + ea[1] * b2f(ga[1][i]);
#pragma unroll
      for (int i = 0; i < 8; i++) a[i] += ea[2] * b2f(ga[2][i]) + ea[3] * b2f(ga[3][i]);
      if (more){
#pragma unroll
        for (int q = 0; q < 4; q++){ ga[q] = gb[q]; ea[q] = eb[q]; }
      }
    }
    for (; j + 4 <= cnt; j += 4){        // 4-edge step
      int j0 = j + half, j1 = j + 2 + half;
      int s0 = __shfl(s, j0), s1 = __shfl(s, j1);
      float e0 = __shfl(ev, j0), e1 = __shfl(ev, j1);
      us8 g0 = *(const us8*)&h[(size_t)s0 * HH + f8];
      us8 g1 = *(const us8*)&h[(size_t)s1 * HH + f8];
#pragma unroll
      for (int i = 0; i < 8; i++) a[i] += e0 * b2f(g0[i]) + e1 * b2f(g1[i]);
    }
    for (; j < cnt; j += 2){             // 0-3 remaining edges
      int jj = j + half;
      int sj = __shfl(s, jj & 63);       // lanes >= cnt hold s=0 -> safe address
      float ejr = __shfl(ev, jj & 63);
      float ej = (jj < cnt) ? ejr : 0.f;
      us8 gj = *(const us8*)&h[(size_t)sj * HH + f8];
#pragma unroll
      for (int i = 0; i < 8; i++) a[i] += ej * b2f(gj[i]);
    }
  }
  for (int off = 32; off > 0; off >>= 1) den += __shfl_xor(den, off);
#pragma unroll
  for (int i = 0; i < 8; i++) a[i] += __shfl_xor(a[i], 32);   // merge even/odd halves
  if (lane < 32){
    float inv = 1.f / den;
    float4 b4a = *(const float4*)&bias[f8];
    float4 b4b = *(const float4*)&bias[f8 + 4];
    us8 o;
    o[0] = f2b(selu_f(a[0] * inv + b4a.x));
    o[1] = f2b(selu_f(a[1] * inv + b4a.y));
    o[2] = f2b(selu_f(a[2] * inv + b4a.z));
    o[3] = f2b(selu_f(a[3] * inv + b4a.w));
    o[4] = f2b(selu_f(a[4] * inv + b4b.x));
    o[5] = f2b(selu_f(a[5] * inv + b4b.y));
    o[6] = f2b(selu_f(a[6] * inv + b4b.z));
    o[7] = f2b(selu_f(a[7] * inv + b4b.w));
    *(us8*)&outp[(size_t)node * HH + f8] = o;
  }
}

// ---------------- fused head: pool + z1 + news + final per graph (binary-searched bounds) ----------------
__global__ __launch_bounds__(256) void head_kernel(const unsigned short* __restrict__ x3,
    const int* __restrict__ batch, const float* __restrict__ x,
    const float* __restrict__ W0, const float* __restrict__ b0,
    const float* __restrict__ Wf1, const float* __restrict__ bf1,
    const float* __restrict__ Wf2, const float* __restrict__ bf2,
    float* __restrict__ out){
  __shared__ float pr[HH];      // pooled (selu applied)
  __shared__ float xr[FF];      // root-node features
  __shared__ float zc[HH];      // concat [z1, news]
  __shared__ int se[2];
  __shared__ float l0s[2], l1s[2];
  int g = blockIdx.x, t = threadIdx.x;
  if (t < 2){                   // graph bounds: first n with batch[n] >= g (+t)
    int target = g + t, lo = 0, hi = NN;
    while (lo < hi){ int mid = (lo + hi) >> 1; if (batch[mid] < target) lo = mid + 1; else hi = mid; }
    se[t] = lo;
  }
  __syncthreads();
  int s = se[0], e = se[1];
  {                             // global mean pool over the graph, feature t
    float acc = 0.f;
    for (int n = s; n < e; n++) acc += b2f(x3[(size_t)n * HH + t]);
    pr[t] = selu_f(acc / (float)(e - s));
  }
  for (int k = t; k < FF; k += 256) xr[k] = x[(size_t)s * FF + k];   // root = first node
  __syncthreads();
  if (t < NHIDD){               // waves 0-1: z1 = selu(pr @ Wf1 + bf1)
    float acc = 0.f;
    for (int k = 0; k < HH; k++) acc += pr[k] * Wf1[k * NHIDD + t];
    zc[t] = selu_f(acc + bf1[t]);
  } else {                      // waves 2-3: news = relu(x_root @ W0 + b0)
    int t2 = t - NHIDD;
    float acc = 0.f;
    for (int k = 0; k < FF; k++) acc += xr[k] * W0[k * NHIDD + t2];
    acc += b0[t2];
    zc[NHIDD + t2] = acc > 0.f ? acc : 0.f;
  }
  __syncthreads();
  if (t < NHIDD){               // z2 = relu(zc @ Wf1 + bf1); logits; 2-wave reduce
    float acc = 0.f;
    for (int k = 0; k < HH; k++) acc += zc[k] * Wf1[k * NHIDD + t];
    float z2 = acc + bf1[t]; z2 = z2 > 0.f ? z2 : 0.f;
    float p0 = z2 * Wf2[t * CC + 0];
    float p1 = z2 * Wf2[t * CC + 1];
    for (int off = 32; off > 0; off >>= 1){ p0 += __shfl_xor(p0, off); p1 += __shfl_xor(p1, off); }
    if ((t & 63) == 0){ l0s[t >> 6] = p0; l1s[t >> 6] = p1; }
  }
  __syncthreads();
  if (t == 0){
    float l0 = l0s[0] + l0s[1] + bf2[0];
    float l1 = l1s[0] + l1s[1] + bf2[1];
    float mx = fmaxf(l0, l1);
    float lse = mx + logf(__expf(l0 - mx) + __expf(l1 - mx));
    out[g * CC + 0] = l0 - lse;
    out[g * CC + 1] = l1 - lse;
  }
}

extern "C" void kernel_launch(void* const* d_in, const int* in_sizes, int n_in,
                              void* d_out, int out_size, void* d_ws, size_t ws_size,
                              hipStream_t stream){
  const float* x          = (const float*)d_in[0];
  const int* edge_index   = (const int*)d_in[1];
  const int* batch        = (const int*)d_in[2];
  const float* W1  = (const float*)d_in[3];
  const float* as1 = (const float*)d_in[4];
  const float* ad1 = (const float*)d_in[5];
  const float* b1  = (const float*)d_in[6];
  const float* W2  = (const float*)d_in[7];
  const float* as2 = (const float*)d_in[8];
  const float* ad2 = (const float*)d_in[9];
  const float* b2  = (const float*)d_in[10];
  const float* W0  = (const float*)d_in[11];
  const float* b0  = (const float*)d_in[12];
  const float* Wf1 = (const float*)d_in[13];
  const float* bf1 = (const float*)d_in[14];
  const float* Wf2 = (const float*)d_in[15];
  const float* bf2 = (const float*)d_in[16];
  float* out = (float*)d_out;

  char* w = (char*)d_ws;
  size_t off = 0;
  auto alloc = [&](size_t bytes){ size_t o = off; off += (bytes + 255) & ~(size_t)255; return o; };
  unsigned short* h    = (unsigned short*)(w + alloc((size_t)NN * HH * 2));   // 25.6 MB
  unsigned short* x2   = (unsigned short*)(w + alloc((size_t)NN * HH * 2));   // 25.6 MB
  unsigned short* Wsw1 = (unsigned short*)(w + alloc((size_t)FF * HH * 2));
  unsigned short* Wsw2 = (unsigned short*)(w + alloc((size_t)HH * HH * 2));
  float* als     = (float*)(w + alloc((size_t)NN * 4));
  float* ald     = (float*)(w + alloc((size_t)NN * 4));
  int*   deg     = (int*)(w + alloc((size_t)NN * 4));
  int*   row_ptr = (int*)(w + alloc((size_t)(NN + 1) * 4));
  int*   fillp   = (int*)(w + alloc((size_t)NN * 4));
  int*   csr_src = (int*)(w + alloc((size_t)ETOT * 4));
  int*   bsum    = (int*)(w + alloc(64 * 4));

  const int* srcA = edge_index;
  const int* dstA = edge_index + EE;

  // weight swizzle (both layers, one dispatch)
  swizzleW2<<<(FF * HH + HH * HH) / 256, 256, 0, stream>>>(W1, W2, Wsw1, Wsw2);

  // CSR build (shared by both GAT layers); deg zeroed via async memset (graph-safe, one fewer dispatch)
  hipMemsetAsync(deg, 0, (size_t)NN * 4, stream);
  deg_kernel<<<(ETOT + 255) / 256, 256, 0, stream>>>(dstA, deg);
  scanA<<<NCHUNK, 256, 0, stream>>>(deg, bsum);
  scanC<<<NCHUNK, 256, 0, stream>>>(deg, bsum, row_ptr, fillp);
  fill_kernel<<<(ETOT + 255) / 256, 256, 0, stream>>>(srcA, dstA, fillp, csr_src);

  const int gemm_grid = (NN + 31) / 32;   // 32-row full-K panels -> 1563 blocks
  // GAT layer 1 (A = fp32 x via DMA, cvt on LDS read; als/ald fused; B pinned live)
  gemm1_f32<<<gemm_grid, 256, 0, stream>>>(x, Wsw1, as1, ad1, h, als, ald, NN);
  agg_wave<<<(NN + 3) / 4, 256, 0, stream>>>(h, als, ald, row_ptr, csr_src, b1, x2);
  // GAT layer 2 (A = bf16 x2)
  gemm_mfma<HH, 3><<<gemm_grid, 256, 0, stream>>>(x2, Wsw2, as2, ad2, h, als, ald, NN);
  agg_wave<<<(NN + 3) / 4, 256, 0, stream>>>(h, als, ald, row_ptr, csr_src, b2, x2);
  // fused head (pool + z1 + news + final; bounds via binary search)
  head_kernel<<<GG, 256, 0, stream>>>(x2, batch, x, W0, b0, Wf1, bf1, Wf2, bf2, out);
}

// Round 9
// 576.605 us; speedup vs baseline: 1.1495x; 1.1495x over previous
//
#include <hip/hip_runtime.h>
#include <hip/hip_bf16.h>
#include <cstdint>
#include <cstddef>

#define NN 50000
#define EE 800000
#define FF 768
#define HH 256
#define GG 512
#define CC 2
#define NHIDD 128
#define ETOT (EE + NN)
#define NCHUNK 49   // ceil(NN/1024)

typedef __attribute__((ext_vector_type(8))) short bf16x8;   // 8 bf16 in 4 VGPRs
typedef __attribute__((ext_vector_type(4))) float f32x4;
typedef __attribute__((ext_vector_type(8))) unsigned short us8;

__device__ __forceinline__ float b2f(unsigned short u){
  union { float f; uint32_t i; } v; v.i = ((uint32_t)u) << 16; return v.f;
}
__device__ __forceinline__ unsigned short f2b(float f){
  uint32_t u = __float_as_uint(f);
  uint32_t r = (u + 0x7fffu + ((u >> 16) & 1u)) >> 16;
  return (unsigned short)r;
}
// packed fp32->bf16 (RNE, same rounding as f2b); gfx950 has the instruction but no builtin
__device__ __forceinline__ uint32_t cvtpk(float a, float b){
  uint32_t d;
  asm volatile("v_cvt_pk_bf16_f32 %0, %1, %2" : "=v"(d) : "v"(a), "v"(b));
  return d;
}
__device__ __forceinline__ float selu_f(float x){
  const float lam = 1.0507009873554805f, alp = 1.6732632423543772f;
  return x > 0.f ? lam * x : lam * alp * (__expf(x) - 1.f);
}

// direct-to-LDS 16B DMA (compiler never auto-emits this; bypasses VGPR round-trip AND regalloc load-sinking)
__device__ __forceinline__ void gload_lds16(const void* g, void* l){
  __builtin_amdgcn_global_load_lds((const __attribute__((address_space(1))) void*)g,
                                   (__attribute__((address_space(3))) void*)l, 16, 0, 0);
}

// ---------------- W1+W2 swizzle in ONE dispatch: [K][256] f32 -> [K/32][256][32] bf16 ----------------
__global__ __launch_bounds__(256) void swizzleW2(const float* __restrict__ W1, const float* __restrict__ W2,
                                                 unsigned short* __restrict__ Wsw1, unsigned short* __restrict__ Wsw2){
  int i = blockIdx.x * 256 + threadIdx.x;          // grid covers FF*HH + HH*HH = 262144 exactly
  if (i < FF * HH){
    int k = i / HH, n = i % HH;
    Wsw1[(size_t)(k >> 5) * 8192 + n * 32 + (k & 31)] = f2b(W1[i]);
  } else {
    int i2 = i - FF * HH;
    int k = i2 / HH, n = i2 % HH;
    Wsw2[(size_t)(k >> 5) * 8192 + n * 32 + (k & 31)] = f2b(W2[i2]);
  }
}

// ---------------- CSR build ----------------
__global__ __launch_bounds__(256) void deg_kernel(const int* __restrict__ dstA, int* __restrict__ deg){
  int i = blockIdx.x * 256 + threadIdx.x;
  if (i < ETOT){
    int d = (i < EE) ? dstA[i] : (i - EE);   // self-loops appended
    atomicAdd(&deg[d], 1);
  }
}

__global__ __launch_bounds__(256) void scanA(const int* __restrict__ deg, int* __restrict__ bsum){
  __shared__ int red[256];
  int c = blockIdx.x, tid = threadIdx.x;
  int base = c * 1024 + tid * 4;
  int s = 0;
#pragma unroll
  for (int j = 0; j < 4; j++){ int idx = base + j; if (idx < NN) s += deg[idx]; }
  red[tid] = s; __syncthreads();
  for (int off = 128; off > 0; off >>= 1){
    if (tid < off) red[tid] += red[tid + off];
    __syncthreads();
  }
  if (tid == 0) bsum[c] = red[0];
}

// scanB folded in: chunk base computed by an in-block reduce of bsum[0..c)
__global__ __launch_bounds__(256) void scanC(const int* __restrict__ deg, const int* __restrict__ bsum,
                                             int* __restrict__ row_ptr, int* __restrict__ fill_ptr){
  __shared__ int ts[256];
  __shared__ int cbase;
  int c = blockIdx.x, tid = threadIdx.x;
  int pb = (tid < c) ? bsum[tid] : 0;    // NCHUNK=49 <= 256
  ts[tid] = pb; __syncthreads();
  for (int off = 128; off > 0; off >>= 1){
    if (tid < off) ts[tid] += ts[tid + off];
    __syncthreads();
  }
  if (tid == 0) cbase = ts[0];
  __syncthreads();
  int base = c * 1024 + tid * 4;
  int v[4]; int s = 0;
#pragma unroll
  for (int j = 0; j < 4; j++){ int idx = base + j; v[j] = (idx < NN) ? deg[idx] : 0; s += v[j]; }
  ts[tid] = s; __syncthreads();
  for (int off = 1; off < 256; off <<= 1){
    int add = (tid >= off) ? ts[tid - off] : 0;
    __syncthreads();
    ts[tid] += add;
    __syncthreads();
  }
  int run = ts[tid] - s + cbase;
#pragma unroll
  for (int j = 0; j < 4; j++){
    int idx = base + j;
    if (idx < NN){ row_ptr[idx] = run; fill_ptr[idx] = run; }
    run += v[j];
  }
  if (c == 0 && tid == 0) row_ptr[NN] = ETOT;
}

__global__ __launch_bounds__(256) void fill_kernel(const int* __restrict__ srcA, const int* __restrict__ dstA,
                                                   int* __restrict__ fill_ptr, int* __restrict__ csr_src){
  int i = blockIdx.x * 256 + threadIdx.x;
  if (i < ETOT){
    int s = (i < EE) ? srcA[i] : (i - EE);
    int d = (i < EE) ? dstA[i] : (i - EE);
    int pos = atomicAdd(&fill_ptr[d], 1);
    csr_src[pos] = s;
  }
}

// ---------------- GEMM layer 1 v8: 512 threads / 8 waves, 32 cols per wave ----------------
// Register prefetch cannot be forced from source on this toolchain (r2,3,5,7). v8 attacks latency the
// other way: LESS state per wave + MORE waves. 8 waves x 32 cols: bcur 16 + acc 16 VGPRs (vs 32+32)
// -> real headroom for compiler-scheduled bnext; occupancy doubles (16 waves/CU @ lb(512,4)).
// A staging (DMA, XOR-swizzled source) and B addressing unchanged from the 580us config.
__global__ __launch_bounds__(512, 4) void gemm1_f32(const float* __restrict__ A,
                                                 const unsigned short* __restrict__ Wsw,
                                                 const float* __restrict__ a_s, const float* __restrict__ a_d,
                                                 unsigned short* __restrict__ out,
                                                 float* __restrict__ als, float* __restrict__ ald, int M){
  __shared__ float Alf[32 * 384];                  // 48 KB (one half-K fp32 panel)
  const int tid = threadIdx.x;
  const int m0 = blockIdx.x * 32;
  const int lane = tid & 63, w = tid >> 6;         // w in [0,8)
  const int koff = (lane >> 4) * 8;
  const int arow = lane & 15;
  const int nrow = w * 32 + (lane & 15);           // B row (n) for ct=0

  f32x4 acc[2][2];
#pragma unroll
  for (int rt = 0; rt < 2; rt++)
#pragma unroll
    for (int ct = 0; ct < 2; ct++) acc[rt][ct] = (f32x4){0.f, 0.f, 0.f, 0.f};

  const unsigned short* bbase = Wsw + ((size_t)nrow * 32 + koff);
  bf16x8 bcur[2][2];

  auto stage_half = [&](int p){
#pragma unroll
    for (int j = 0; j < 6; j++){                   // 32 rows x 96 chunks = 3072 = 6 x 512
      int L16 = j * 512 + tid;                     // linear 16B(f32x4)-chunk index in half-panel
      int row = L16 / 96;
      int ch  = L16 - row * 96;
      int sch = ch ^ (row & 7);                    // inverse-swizzle the SOURCE (involution)
      int gr  = m0 + row; if (gr >= M) gr = M - 1; // clamp: garbage rows never stored
      gload_lds16(A + (size_t)gr * FF + p * 384 + sch * 4,
                  Alf + (size_t)(j * 512 + w * 64) * 4);   // wave-uniform dest; HW adds lane*16B
    }
  };

#pragma unroll
  for (int p = 0; p < 2; p++){
    if (p == 1) __syncthreads();                   // all phase-0 reads done before overwrite
    stage_half(p);
    // prefetch B slabs for first ks of this phase (overlaps DMA drain)
#pragma unroll
    for (int k2 = 0; k2 < 2; k2++)
#pragma unroll
      for (int ct = 0; ct < 2; ct++)
        bcur[k2][ct] = *(const bf16x8*)(bbase + (size_t)(p * 12 + k2) * 8192 + ct * 512);
    __syncthreads();                               // DMA visible

    for (int ks = 0; ks < 6; ks++){
      bf16x8 bnext[2][2];
      if (ks + 1 < 6){
#pragma unroll
        for (int k2 = 0; k2 < 2; k2++)
#pragma unroll
          for (int ct = 0; ct < 2; ct++)
            bnext[k2][ct] = *(const bf16x8*)(bbase + (size_t)(p * 12 + (ks + 1) * 2 + k2) * 8192 + ct * 512);
      }
      bf16x8 af[2][2];
#pragma unroll
      for (int k2 = 0; k2 < 2; k2++)
#pragma unroll
        for (int rt = 0; rt < 2; rt++){
          int R = rt * 16 + arow;
          int c = ks * 16 + k2 * 8 + (lane >> 4) * 2;          // even chunk index of 8-f32 fragment
          int m = R & 7;
          float4 v0 = *(const float4*)&Alf[R * 384 + ((c)     ^ m) * 4];
          float4 v1 = *(const float4*)&Alf[R * 384 + ((c + 1) ^ m) * 4];
          union { bf16x8 v; uint32_t u[4]; } X;
          X.u[0] = cvtpk(v0.x, v0.y); X.u[1] = cvtpk(v0.z, v0.w);
          X.u[2] = cvtpk(v1.x, v1.y); X.u[3] = cvtpk(v1.z, v1.w);
          af[k2][rt] = X.v;
        }
#pragma unroll
      for (int k2 = 0; k2 < 2; k2++)
#pragma unroll
        for (int rt = 0; rt < 2; rt++)
#pragma unroll
          for (int ct = 0; ct < 2; ct++)
            acc[rt][ct] = __builtin_amdgcn_mfma_f32_16x16x32_bf16(af[k2][rt], bcur[k2][ct], acc[rt][ct], 0, 0, 0);
      if (ks + 1 < 6){
#pragma unroll
        for (int k2 = 0; k2 < 2; k2++)
#pragma unroll
          for (int ct = 0; ct < 2; ct++) bcur[k2][ct] = bnext[k2][ct];
      }
    }
  }

  // ---- C write (bf16 h): wave w covers cols [32w, 32w+32) ----
#pragma unroll
  for (int rt = 0; rt < 2; rt++){
    int mbase = m0 + rt * 16 + (lane >> 4) * 4;
#pragma unroll
    for (int r = 0; r < 4; r++){
      int m = mbase + r;
      if (m < M){
        size_t ro = (size_t)m * HH + w * 32 + (lane & 15);
        out[ro + 0]  = f2b(acc[rt][0][r]);
        out[ro + 16] = f2b(acc[rt][1][r]);
      }
    }
  }

  // ---- fused als/ald from fp32 accumulators ----
  float as_c[2], ad_c[2];
#pragma unroll
  for (int ct = 0; ct < 2; ct++){
    int col = w * 32 + ct * 16 + (lane & 15);
    as_c[ct] = a_s[col]; ad_c[ct] = a_d[col];
  }
  float ps[2][4], pd[2][4];
#pragma unroll
  for (int rt = 0; rt < 2; rt++)
#pragma unroll
    for (int r = 0; r < 4; r++){
      float s = 0.f, d = 0.f;
#pragma unroll
      for (int ct = 0; ct < 2; ct++){ float v = acc[rt][ct][r]; s += v * as_c[ct]; d += v * ad_c[ct]; }
      ps[rt][r] = s; pd[rt][r] = d;
    }
#pragma unroll
  for (int off = 1; off < 16; off <<= 1){
#pragma unroll
    for (int rt = 0; rt < 2; rt++)
#pragma unroll
      for (int r = 0; r < 4; r++){
        ps[rt][r] += __shfl_xor(ps[rt][r], off);
        pd[rt][r] += __shfl_xor(pd[rt][r], off);
      }
  }
  __syncthreads();                       // all waves done reading Alf -> safe to repurpose
  float* red = Alf;                      // [2][8 waves][32 rows] = 512 floats
  if ((lane & 15) == 0){
    int q = lane >> 4;
#pragma unroll
    for (int rt = 0; rt < 2; rt++)
#pragma unroll
      for (int r = 0; r < 4; r++){
        int row = rt * 16 + q * 4 + r;
        red[w * 32 + row]       = ps[rt][r];
        red[256 + w * 32 + row] = pd[rt][r];
      }
  }
  __syncthreads();
  if (tid < 32){
    float s = 0.f, d = 0.f;
#pragma unroll
    for (int ww = 0; ww < 8; ww++){
      s += red[ww * 32 + tid];
      d += red[256 + ww * 32 + tid];
    }
    int m = m0 + tid;
    if (m < M){ als[m] = s; ald[m] = d; }
  }
}

// ---------------- GEMM layer 2 (bf16 A, frozen round-6 structure) ----------------
template<int K, int MINW>
__global__ __launch_bounds__(256, MINW) void gemm_mfma(const unsigned short* __restrict__ A,
                                                 const unsigned short* __restrict__ Wsw,
                                                 const float* __restrict__ a_s, const float* __restrict__ a_d,
                                                 unsigned short* __restrict__ out,
                                                 float* __restrict__ als, float* __restrict__ ald, int M){
  constexpr int CHROW = K / 8;
  __shared__ unsigned short Al[32 * K];
  const int tid = threadIdx.x;
  const int m0 = blockIdx.x * 32;
  const int lane = tid & 63, w = tid >> 6;
  const int koff = (lane >> 4) * 8;
  const int arow = lane & 15;
  const int nrow = w * 64 + (lane & 15);

  f32x4 acc[2][4];
#pragma unroll
  for (int rt = 0; rt < 2; rt++)
#pragma unroll
    for (int ct = 0; ct < 4; ct++) acc[rt][ct] = (f32x4){0.f, 0.f, 0.f, 0.f};

  constexpr int ROUNDS = (32 * CHROW) / 256;
#pragma unroll
  for (int j = 0; j < ROUNDS; j++){
    int L16 = j * 256 + tid;
    int row = L16 / CHROW;
    int ch  = L16 - row * CHROW;
    int sch = ch ^ (row & 7);
    int gr  = m0 + row; if (gr >= M) gr = M - 1;
    gload_lds16(A + (size_t)gr * K + sch * 8,
                &Al[(size_t)(j * 256 + w * 64) * 8]);
  }

  const unsigned short* bbase = Wsw + ((size_t)nrow * 32 + koff);
  bf16x8 bcur[2][4];
#pragma unroll
  for (int k2 = 0; k2 < 2; k2++)
#pragma unroll
    for (int ct = 0; ct < 4; ct++)
      bcur[k2][ct] = *(const bf16x8*)(bbase + (size_t)k2 * 8192 + ct * 512);

  __syncthreads();

  constexpr int NIT = K / 64;
  for (int ks = 0; ks < NIT; ks++){
    bf16x8 bnext[2][4];
    if (ks + 1 < NIT){
#pragma unroll
      for (int k2 = 0; k2 < 2; k2++)
#pragma unroll
        for (int ct = 0; ct < 4; ct++)
          bnext[k2][ct] = *(const bf16x8*)(bbase + (size_t)((ks + 1) * 2 + k2) * 8192 + ct * 512);
    }
    bf16x8 af[2][2];
#pragma unroll
    for (int k2 = 0; k2 < 2; k2++)
#pragma unroll
      for (int rt = 0; rt < 2; rt++){
        int R = rt * 16 + arow;
        int chb = (ks * 8 + k2 * 4 + (lane >> 4)) ^ (R & 7);
        af[k2][rt] = *(const bf16x8*)&Al[(size_t)R * K + chb * 8];
      }
#pragma unroll
    for (int k2 = 0; k2 < 2; k2++)
#pragma unroll
      for (int rt = 0; rt < 2; rt++)
#pragma unroll
        for (int ct = 0; ct < 4; ct++)
          acc[rt][ct] = __builtin_amdgcn_mfma_f32_16x16x32_bf16(af[k2][rt], bcur[k2][ct], acc[rt][ct], 0, 0, 0);
    if (ks + 1 < NIT){
#pragma unroll
      for (int k2 = 0; k2 < 2; k2++)
#pragma unroll
        for (int ct = 0; ct < 4; ct++) bcur[k2][ct] = bnext[k2][ct];
    }
  }

#pragma unroll
  for (int rt = 0; rt < 2; rt++){
    int mbase = m0 + rt * 16 + (lane >> 4) * 4;
#pragma unroll
    for (int r = 0; r < 4; r++){
      int m = mbase + r;
      if (m < M){
        size_t ro = (size_t)m * HH + w * 64 + (lane & 15);
        out[ro + 0]  = f2b(acc[rt][0][r]);
        out[ro + 16] = f2b(acc[rt][1][r]);
        out[ro + 32] = f2b(acc[rt][2][r]);
        out[ro + 48] = f2b(acc[rt][3][r]);
      }
    }
  }

  float as_c[4], ad_c[4];
#pragma unroll
  for (int ct = 0; ct < 4; ct++){
    int col = w * 64 + ct * 16 + (lane & 15);
    as_c[ct] = a_s[col]; ad_c[ct] = a_d[col];
  }
  float ps[2][4], pd[2][4];
#pragma unroll
  for (int rt = 0; rt < 2; rt++)
#pragma unroll
    for (int r = 0; r < 4; r++){
      float s = 0.f, d = 0.f;
#pragma unroll
      for (int ct = 0; ct < 4; ct++){ float v = acc[rt][ct][r]; s += v * as_c[ct]; d += v * ad_c[ct]; }
      ps[rt][r] = s; pd[rt][r] = d;
    }
#pragma unroll
  for (int off = 1; off < 16; off <<= 1){
#pragma unroll
    for (int rt = 0; rt < 2; rt++)
#pragma unroll
      for (int r = 0; r < 4; r++){
        ps[rt][r] += __shfl_xor(ps[rt][r], off);
        pd[rt][r] += __shfl_xor(pd[rt][r], off);
      }
  }
  __syncthreads();
  float* red = (float*)Al;
  if ((lane & 15) == 0){
    int q = lane >> 4;
#pragma unroll
    for (int rt = 0; rt < 2; rt++)
#pragma unroll
      for (int r = 0; r < 4; r++){
        int row = rt * 16 + q * 4 + r;
        red[w * 32 + row]       = ps[rt][r];
        red[128 + w * 32 + row] = pd[rt][r];
      }
  }
  __syncthreads();
  if (tid < 32){
    float s = red[tid] + red[32 + tid] + red[64 + tid] + red[96 + tid];
    float d = red[128 + tid] + red[160 + tid] + red[192 + tid] + red[224 + tid];
    int m = m0 + tid;
    if (m < M){ als[m] = s; ald[m] = d; }
  }
}

// ---------------- agg v4 (round-6 version): 8 edges/step, 4 gather-loads in flight ----------------
__global__ __launch_bounds__(256) void agg_wave(const unsigned short* __restrict__ h,
    const float* __restrict__ als, const float* __restrict__ ald,
    const int* __restrict__ row_ptr, const int* __restrict__ csr_src,
    const float* __restrict__ bias, unsigned short* __restrict__ outp){
  int node = blockIdx.x * 4 + (threadIdx.x >> 6);
  int lane = threadIdx.x & 63;
  if (node >= NN) return;
  int base = row_ptr[node];
  int deg  = row_ptr[node + 1] - base;
  float aldd = ald[node];
  float den = 0.f;
  float a[8] = {0.f, 0.f, 0.f, 0.f, 0.f, 0.f, 0.f, 0.f};
  const int f8 = (lane & 31) * 8;        // this lane's 8-feature slice
  const int half = lane >> 5;            // 0: even edges, 1: odd edges
  for (int p0 = 0; p0 < deg; p0 += 64){
    int cnt = min(64, deg - p0);         // wave-uniform
    float ev = 0.f; int s = 0;
    if (lane < cnt){
      s = csr_src[base + p0 + lane];
      float v = als[s] + aldd;
      v = v > 0.f ? v : 0.2f * v;        // leaky_relu(0.2)
      ev = __expf(v);
    }
    den += ev;
    int j = 0;
    for (; j + 8 <= cnt; j += 8){        // 8 edges/step, 4 loads issued before consume
      int j0 = j + half, j1 = j + 2 + half, j2 = j + 4 + half, j3 = j + 6 + half;
      int s0 = __shfl(s, j0), s1 = __shfl(s, j1), s2 = __shfl(s, j2), s3 = __shfl(s, j3);
      float e0 = __shfl(ev, j0), e1 = __shfl(ev, j1), e2 = __shfl(ev, j2), e3 = __shfl(ev, j3);
      us8 g0 = *(const us8*)&h[(size_t)s0 * HH + f8];
      us8 g1 = *(const us8*)&h[(size_t)s1 * HH + f8];
      us8 g2 = *(const us8*)&h[(size_t)s2 * HH + f8];
      us8 g3 = *(const us8*)&h[(size_t)s3 * HH + f8];
#pragma unroll
      for (int i = 0; i < 8; i++) a[i] += e0 * b2f(g0[i]) + e1 * b2f(g1[i]);
#pragma unroll
      for (int i = 0; i < 8; i++) a[i] += e2 * b2f(g2[i]) + e3 * b2f(g3[i]);
    }
    for (; j + 4 <= cnt; j += 4){        // 4-edge step
      int j0 = j + half, j1 = j + 2 + half;
      int s0 = __shfl(s, j0), s1 = __shfl(s, j1);
      float e0 = __shfl(ev, j0), e1 = __shfl(ev, j1);
      us8 g0 = *(const us8*)&h[(size_t)s0 * HH + f8];
      us8 g1 = *(const us8*)&h[(size_t)s1 * HH + f8];
#pragma unroll
      for (int i = 0; i < 8; i++) a[i] += e0 * b2f(g0[i]) + e1 * b2f(g1[i]);
    }
    for (; j < cnt; j += 2){             // 0-3 remaining edges
      int jj = j + half;
      int sj = __shfl(s, jj & 63);       // lanes >= cnt hold s=0 -> safe address
      float ejr = __shfl(ev, jj & 63);
      float ej = (jj < cnt) ? ejr : 0.f;
      us8 gj = *(const us8*)&h[(size_t)sj * HH + f8];
#pragma unroll
      for (int i = 0; i < 8; i++) a[i] += ej * b2f(gj[i]);
    }
  }
  for (int off = 32; off > 0; off >>= 1) den += __shfl_xor(den, off);
#pragma unroll
  for (int i = 0; i < 8; i++) a[i] += __shfl_xor(a[i], 32);   // merge even/odd halves
  if (lane < 32){
    float inv = 1.f / den;
    float4 b4a = *(const float4*)&bias[f8];
    float4 b4b = *(const float4*)&bias[f8 + 4];
    us8 o;
    o[0] = f2b(selu_f(a[0] * inv + b4a.x));
    o[1] = f2b(selu_f(a[1] * inv + b4a.y));
    o[2] = f2b(selu_f(a[2] * inv + b4a.z));
    o[3] = f2b(selu_f(a[3] * inv + b4a.w));
    o[4] = f2b(selu_f(a[4] * inv + b4b.x));
    o[5] = f2b(selu_f(a[5] * inv + b4b.y));
    o[6] = f2b(selu_f(a[6] * inv + b4b.z));
    o[7] = f2b(selu_f(a[7] * inv + b4b.w));
    *(us8*)&outp[(size_t)node * HH + f8] = o;
  }
}

// ---------------- fused head: pool + z1 + news + final per graph (binary-searched bounds) ----------------
__global__ __launch_bounds__(256) void head_kernel(const unsigned short* __restrict__ x3,
    const int* __restrict__ batch, const float* __restrict__ x,
    const float* __restrict__ W0, const float* __restrict__ b0,
    const float* __restrict__ Wf1, const float* __restrict__ bf1,
    const float* __restrict__ Wf2, const float* __restrict__ bf2,
    float* __restrict__ out){
  __shared__ float pr[HH];      // pooled (selu applied)
  __shared__ float xr[FF];      // root-node features
  __shared__ float zc[HH];      // concat [z1, news]
  __shared__ int se[2];
  __shared__ float l0s[2], l1s[2];
  int g = blockIdx.x, t = threadIdx.x;
  if (t < 2){                   // graph bounds: first n with batch[n] >= g (+t)
    int target = g + t, lo = 0, hi = NN;
    while (lo < hi){ int mid = (lo + hi) >> 1; if (batch[mid] < target) lo = mid + 1; else hi = mid; }
    se[t] = lo;
  }
  __syncthreads();
  int s = se[0], e = se[1];
  {                             // global mean pool over the graph, feature t
    float acc = 0.f;
    for (int n = s; n < e; n++) acc += b2f(x3[(size_t)n * HH + t]);
    pr[t] = selu_f(acc / (float)(e - s));
  }
  for (int k = t; k < FF; k += 256) xr[k] = x[(size_t)s * FF + k];   // root = first node
  __syncthreads();
  if (t < NHIDD){               // waves 0-1: z1 = selu(pr @ Wf1 + bf1)
    float acc = 0.f;
    for (int k = 0; k < HH; k++) acc += pr[k] * Wf1[k * NHIDD + t];
    zc[t] = selu_f(acc + bf1[t]);
  } else {                      // waves 2-3: news = relu(x_root @ W0 + b0)
    int t2 = t - NHIDD;
    float acc = 0.f;
    for (int k = 0; k < FF; k++) acc += xr[k] * W0[k * NHIDD + t2];
    acc += b0[t2];
    zc[NHIDD + t2] = acc > 0.f ? acc : 0.f;
  }
  __syncthreads();
  if (t < NHIDD){               // z2 = relu(zc @ Wf1 + bf1); logits; 2-wave reduce
    float acc = 0.f;
    for (int k = 0; k < HH; k++) acc += zc[k] * Wf1[k * NHIDD + t];
    float z2 = acc + bf1[t]; z2 = z2 > 0.f ? z2 : 0.f;
    float p0 = z2 * Wf2[t * CC + 0];
    float p1 = z2 * Wf2[t * CC + 1];
    for (int off = 32; off > 0; off >>= 1){ p0 += __shfl_xor(p0, off); p1 += __shfl_xor(p1, off); }
    if ((t & 63) == 0){ l0s[t >> 6] = p0; l1s[t >> 6] = p1; }
  }
  __syncthreads();
  if (t == 0){
    float l0 = l0s[0] + l0s[1] + bf2[0];
    float l1 = l1s[0] + l1s[1] + bf2[1];
    float mx = fmaxf(l0, l1);
    float lse = mx + logf(__expf(l0 - mx) + __expf(l1 - mx));
    out[g * CC + 0] = l0 - lse;
    out[g * CC + 1] = l1 - lse;
  }
}

extern "C" void kernel_launch(void* const* d_in, const int* in_sizes, int n_in,
                              void* d_out, int out_size, void* d_ws, size_t ws_size,
                              hipStream_t stream){
  const float* x          = (const float*)d_in[0];
  const int* edge_index   = (const int*)d_in[1];
  const int* batch        = (const int*)d_in[2];
  const float* W1  = (const float*)d_in[3];
  const float* as1 = (const float*)d_in[4];
  const float* ad1 = (const float*)d_in[5];
  const float* b1  = (const float*)d_in[6];
  const float* W2  = (const float*)d_in[7];
  const float* as2 = (const float*)d_in[8];
  const float* ad2 = (const float*)d_in[9];
  const float* b2  = (const float*)d_in[10];
  const float* W0  = (const float*)d_in[11];
  const float* b0  = (const float*)d_in[12];
  const float* Wf1 = (const float*)d_in[13];
  const float* bf1 = (const float*)d_in[14];
  const float* Wf2 = (const float*)d_in[15];
  const float* bf2 = (const float*)d_in[16];
  float* out = (float*)d_out;

  char* w = (char*)d_ws;
  size_t off = 0;
  auto alloc = [&](size_t bytes){ size_t o = off; off += (bytes + 255) & ~(size_t)255; return o; };
  unsigned short* h    = (unsigned short*)(w + alloc((size_t)NN * HH * 2));   // 25.6 MB
  unsigned short* x2   = (unsigned short*)(w + alloc((size_t)NN * HH * 2));   // 25.6 MB
  unsigned short* Wsw1 = (unsigned short*)(w + alloc((size_t)FF * HH * 2));
  unsigned short* Wsw2 = (unsigned short*)(w + alloc((size_t)HH * HH * 2));
  float* als     = (float*)(w + alloc((size_t)NN * 4));
  float* ald     = (float*)(w + alloc((size_t)NN * 4));
  int*   deg     = (int*)(w + alloc((size_t)NN * 4));
  int*   row_ptr = (int*)(w + alloc((size_t)(NN + 1) * 4));
  int*   fillp   = (int*)(w + alloc((size_t)NN * 4));
  int*   csr_src = (int*)(w + alloc((size_t)ETOT * 4));
  int*   bsum    = (int*)(w + alloc(64 * 4));

  const int* srcA = edge_index;
  const int* dstA = edge_index + EE;

  // weight swizzle (both layers, one dispatch)
  swizzleW2<<<(FF * HH + HH * HH) / 256, 256, 0, stream>>>(W1, W2, Wsw1, Wsw2);

  // CSR build (shared by both GAT layers)
  hipMemsetAsync(deg, 0, (size_t)NN * 4, stream);
  deg_kernel<<<(ETOT + 255) / 256, 256, 0, stream>>>(dstA, deg);
  scanA<<<NCHUNK, 256, 0, stream>>>(deg, bsum);
  scanC<<<NCHUNK, 256, 0, stream>>>(deg, bsum, row_ptr, fillp);
  fill_kernel<<<(ETOT + 255) / 256, 256, 0, stream>>>(srcA, dstA, fillp, csr_src);

  const int gemm_grid = (NN + 31) / 32;   // 32-row full-K panels -> 1563 blocks
  // GAT layer 1 (A = fp32 x via DMA, cvt on LDS read; als/ald fused; 512-thread/8-wave)
  gemm1_f32<<<gemm_grid, 512, 0, stream>>>(x, Wsw1, as1, ad1, h, als, ald, NN);
  agg_wave<<<(NN + 3) / 4, 256, 0, stream>>>(h, als, ald, row_ptr, csr_src, b1, x2);
  // GAT layer 2 (A = bf16 x2)
  gemm_mfma<HH, 3><<<gemm_grid, 256, 0, stream>>>(x2, Wsw2, as2, ad2, h, als, ald, NN);
  agg_wave<<<(NN + 3) / 4, 256, 0, stream>>>(h, als, ald, row_ptr, csr_src, b2, x2);
  // fused head (pool + z1 + news + final; bounds via binary search)
  head_kernel<<<GG, 256, 0, stream>>>(x2, batch, x, W0, b0, Wf1, bf1, Wf2, bf2, out);
}